// Round 12
// baseline (1847.330 us; speedup 1.0000x reference)
//
#include <hip/hip_runtime.h>

// SLabLinearAttention: B=4 N=4096 C=1024 H=16 HD=64 KH=5
// Round 12: (a) GEMMs at BK=32 / 64KB LDS -> 2 blocks/CU (TLP experiment; de-fenced
//               2-barrier loop from R10 kept verbatim in structure),
//           (b) epilogues restructured into 64KB passes,
//           (c) kv_mfma + kv_red fused (no part buffer).

#define BB   4
#define NN   4096
#define CDIM 1024
#define NH   16
#define HDIM 64
#define BH   64

typedef __attribute__((ext_vector_type(8))) short short8;
typedef __attribute__((ext_vector_type(4))) float f32x4;
typedef unsigned short u16;

__device__ __forceinline__ float b2f(short s) {
    union { unsigned u; float f; } c;
    c.u = ((unsigned)(unsigned short)s) << 16;
    return c.f;
}
__device__ __forceinline__ u16 f2b(float f) {   // RNE
    unsigned u = __float_as_uint(f);
    return (u16)((u + 0x7fffu + ((u >> 16) & 1u)) >> 16);
}
__device__ __forceinline__ void gload16(const void* g, void* l) {
    __builtin_amdgcn_global_load_lds((const __attribute__((address_space(1))) void*)g,
                                     (__attribute__((address_space(3))) void*)l, 16, 0, 0);
}

__global__ __launch_bounds__(256) void k_fill_diag(float* __restrict__ out, int n, float val)
{
    int i = blockIdx.x * 256 + threadIdx.x;
    if (i < n) out[i] = val;
}

// fused convert: x (4194304 f4) | qkv_w (786432 f4) | proj_w (262144 f4)
__global__ __launch_bounds__(256) void k_convert_all(
    const float* __restrict__ x, const float* __restrict__ qw, const float* __restrict__ pw,
    u16* __restrict__ xb, u16* __restrict__ qwb, u16* __restrict__ pwb)
{
    int i = blockIdx.x * 256 + threadIdx.x;
    const float* src; u16* dst; int j;
    if (i < 4194304)      { src = x;  dst = xb;  j = i; }
    else if (i < 4980736) { src = qw; dst = qwb; j = i - 4194304; }
    else                  { src = pw; dst = pwb; j = i - 4980736; }
    float4 v = reinterpret_cast<const float4*>(src)[j];
    ushort4 o;
    o.x = f2b(v.x); o.y = f2b(v.y); o.z = f2b(v.z); o.w = f2b(v.w);
    reinterpret_cast<ushort4*>(dst)[j] = o;
}

// ======= de-fenced 2-barrier 256x256 BK=32 GEMM core (64KB LDS, 2 blk/CU) =======
// LDS (u16): buf b @ b*16384; A @ +0 (16KB), B @ +8192 elems (16KB).
// phys chunk = chunk ^ ((row>>1)&3); pre-swizzled global src, swizzled ds_read.
// Ledger: iter kt reads buf[kt&1]; after barrier (a) (all waves' reads retired via
// their MFMA lgkm-waits) STG(kt+2) overwrites buf[kt&1]; vmcnt(4) at boundary
// leaves only kt+2's 4 loads outstanding => kt+1 landed; barrier (b) publishes.
#define GEMM256_B32()                                                                    \
    const int t = threadIdx.x;                                                           \
    const int l = t & 63, w = t >> 6;                                                    \
    const int wr = w >> 2, wc = w & 3;                                                   \
    const int fr = l & 15;                                                               \
    const int physE  = ((l >> 4) ^ ((fr >> 1) & 3)) * 8;                                 \
    const int qa     = ((l & 3) ^ ((l >> 3) & 3)) * 8;                                   \
    const int aRow   = w * 16 + (l >> 2);                                                \
    const u16* gA0 = A  + (size_t)(brow + aRow) * 1024 + qa;                             \
    const u16* gB0 = Bw + (size_t)(bcol + aRow) * 1024 + qa;                             \
    char* ldsc = (char*)lds;                                                             \
    const int afBase = (wr * 128 + fr) * 32 + physE;                                     \
    const int bfBase = 8192 + (wc * 64 + fr) * 32 + physE;                               \
    f32x4 acc[8][4];                                                                     \
    _Pragma("unroll")                                                                    \
    for (int m = 0; m < 8; ++m)                                                          \
        _Pragma("unroll")                                                                \
        for (int n = 0; n < 4; ++n) acc[m][n] = (f32x4){0.f, 0.f, 0.f, 0.f};             \
    auto STG = [&](int kt) {                                                             \
        const u16* ga = gA0 + kt * 32;                                                   \
        const u16* gb = gB0 + kt * 32;                                                   \
        char* d = ldsc + (kt & 1) * 32768 + t * 16;                                      \
        gload16(ga,          d);                                                         \
        gload16(ga + 131072, d + 8192);                                                  \
        gload16(gb,          d + 16384);                                                 \
        gload16(gb + 131072, d + 24576);                                                 \
    };                                                                                   \
    STG(0); STG(1);                                                                      \
    asm volatile("s_waitcnt vmcnt(4)" ::: "memory");                                     \
    __builtin_amdgcn_s_barrier();                                                        \
    _Pragma("unroll 1")                                                                  \
    for (int kt = 0; kt < 32; ++kt) {                                                    \
        const int B0 = (kt & 1) * 16384;                                                 \
        short8 af[8], bf[4];                                                             \
        _Pragma("unroll")                                                                \
        for (int n = 0; n < 4; ++n)                                                      \
            bf[n] = *reinterpret_cast<const short8*>(&lds[B0 + bfBase + n * 512]);       \
        _Pragma("unroll")                                                                \
        for (int m = 0; m < 8; ++m)                                                      \
            af[m] = *reinterpret_cast<const short8*>(&lds[B0 + afBase + m * 512]);       \
        __builtin_amdgcn_s_setprio(1);                                                   \
        _Pragma("unroll")                                                                \
        for (int m = 0; m < 8; ++m)                                                      \
            _Pragma("unroll")                                                            \
            for (int n = 0; n < 4; ++n)                                                  \
                acc[m][n] = __builtin_amdgcn_mfma_f32_16x16x32_bf16(af[m], bf[n], acc[m][n], 0, 0, 0); \
        __builtin_amdgcn_s_setprio(0);                                                   \
        __builtin_amdgcn_s_barrier();   /* (a) reads of buf[kt&1] retired */             \
        if (kt + 2 < 32) STG(kt + 2);                                                    \
        if (kt < 30) { asm volatile("s_waitcnt vmcnt(4)" ::: "memory"); }                \
        else         { asm volatile("s_waitcnt vmcnt(0)" ::: "memory"); }                \
        __builtin_amdgcn_s_barrier();   /* (b) tile kt+1 published */                    \
    }

// ---------------- GEMM1: [16384,3072] = x @ qkv_w^T, 64KB half-pass epilogue -----------
// Outputs: q_b[bh][j][d], v_b[bh][j][d] (row-major); ktg[bh][c][j], vtg[bh][d][j].
__global__ __launch_bounds__(512, 4) void k_gemm1_256(
    const u16* __restrict__ A, const u16* __restrict__ Bw,
    const float* __restrict__ bias, const float* __restrict__ pos_enc,
    u16* __restrict__ q, u16* __restrict__ ktg, u16* __restrict__ v, u16* __restrict__ vtg)
{
    __shared__ u16 lds[32768];   // 64KB: K-loop dbuf, then 128x256 u16 C-half
    const int lid = blockIdx.y * 12 + blockIdx.x;            // nwg = 768, %8==0
    const int swz = (lid & 7) * 96 + (lid >> 3);
    const int bcol = (swz % 12) * 256;
    const int brow = (swz / 12) * 256;

    GEMM256_B32()

    const int part = bcol >> 10;                 // 0=q 1=k 2=v, uniform per block
    const int b_ = brow >> 12, i0 = brow & 4095;
    #pragma unroll 1
    for (int half = 0; half < 2; ++half) {
        __syncthreads();
        if (wr == half) {
            const int row_l = (l >> 4) * 4;
            const int col_l = wc * 64 + fr;
            #pragma unroll
            for (int n = 0; n < 4; ++n) {
                const int col = col_l + n * 16;
                const int gc = bcol + col;
                const int c = gc & 1023;
                float bv = bias[gc];
                if (part == 1) bv += pos_enc[c];
                const int cc = col >> 3, in = col & 7;
                #pragma unroll
                for (int m = 0; m < 8; ++m)
                    #pragma unroll
                    for (int j = 0; j < 4; ++j) {
                        const int row = m * 16 + row_l + j;          // 0..127
                        float val = acc[m][n][j] + bv;
                        if (part != 2) val = fmaxf(val, 0.f);
                        lds[row * 256 + ((cc ^ (row & 7)) << 3) + in] = f2b(val);
                    }
            }
        }
        __syncthreads();
        if (part != 1) {
            u16* dst = (part == 0) ? q : v;
            #pragma unroll
            for (int it = 0; it < 8; ++it) {
                const int id = it * 512 + t;                 // 0..4095
                const int row = id >> 5, cc = id & 31;
                short8 val = *reinterpret_cast<const short8*>(&lds[row * 256 + ((cc ^ (row & 7)) << 3)]);
                const int c2 = (bcol + cc * 8) & 1023;
                const int h2 = c2 >> 6, d2 = c2 & 63;
                *reinterpret_cast<short8*>(
                    &dst[((size_t)(b_ * NH + h2) * NN + i0 + half * 128 + row) * HDIM + d2]) = val;
            }
        }
        if (part != 0) {
            u16* dstT = (part == 1) ? ktg : vtg;
            #pragma unroll
            for (int it = 0; it < 8; ++it) {
                const int id = it * 512 + t;                 // 0..4095
                const int cl = id & 255, jc = id >> 8;       // c-local, j-chunk (8 rows)
                short8 vv;
                #pragma unroll
                for (int rr = 0; rr < 8; ++rr)
                    vv[rr] = (short)lds[(jc * 8 + rr) * 256 + (((cl >> 3) ^ rr) << 3) + (cl & 7)];
                const int c2 = (bcol + cl) & 1023;
                const int h2 = c2 >> 6, d2 = c2 & 63;
                *reinterpret_cast<short8*>(
                    &dstT[((size_t)(b_ * NH + h2) * HDIM + d2) * NN + i0 + half * 128 + jc * 8]) = vv;
            }
        }
    }
}

// ---------------- GEMM2: [16384,1024] = out2 @ proj_w^T + b, 64KB quarter-pass ---------
__global__ __launch_bounds__(512, 4) void k_gemm2_256(
    const u16* __restrict__ A, const u16* __restrict__ Bw,
    const float* __restrict__ bias, float* __restrict__ out)
{
    __shared__ u16 lds[32768];   // 64KB: K-loop dbuf, then 64x256 fp32 C-quarter
    const int lid = blockIdx.y * 4 + blockIdx.x;             // nwg = 256, %8==0
    const int swz = (lid & 7) * 32 + (lid >> 3);
    const int bcol = (swz % 4) * 256;
    const int brow = (swz / 4) * 256;

    GEMM256_B32()

    float* ldsf = reinterpret_cast<float*>(lds);     // 16384 floats = 64 rows x 256
    #pragma unroll 1
    for (int qp = 0; qp < 4; ++qp) {
        __syncthreads();
        if (wr == (qp >> 1)) {
            const int m0 = (qp & 1) * 4;
            const int row_l = (l >> 4) * 4;
            const int col_l = wc * 64 + fr;
            #pragma unroll
            for (int n = 0; n < 4; ++n) {
                const int col = col_l + n * 16;
                const float bv = bias[bcol + col];
                #pragma unroll
                for (int mm = 0; mm < 4; ++mm)
                    #pragma unroll
                    for (int j = 0; j < 4; ++j) {
                        const int row = mm * 16 + row_l + j;     // 0..63
                        ldsf[row * 256 + (col ^ (((row >> 2) & 3) << 3))] = acc[m0 + mm][n][j] + bv;
                    }
            }
        }
        __syncthreads();
        const float4* ldsf4 = reinterpret_cast<const float4*>(ldsf);
        #pragma unroll
        for (int it = 0; it < 8; ++it) {
            const int id = it * 512 + t;                 // 0..4095
            const int row = id >> 6, cc4 = id & 63;
            float4 vv = ldsf4[row * 64 + (cc4 ^ (((row >> 2) & 3) << 1))];
            *reinterpret_cast<float4*>(
                &out[(size_t)(brow + qp * 64 + row) * CDIM + bcol + cc4 * 4]) = vv;
        }
    }
}

// ---------------- K2: fused kv via MFMA + in-LDS reduction -> kvt bf16 ----------------
__global__ __launch_bounds__(256) void k_kv_fused(
    const u16* __restrict__ ktg, const u16* __restrict__ vtg,
    u16* __restrict__ kvt)
{
    __shared__ float red[4][5120];   // 80 KB
    const int t = threadIdx.x, l = t & 63, w = t >> 6;
    const int bh = blockIdx.x;
    const u16* kb = ktg + (size_t)bh * HDIM * NN;
    const u16* vb = vtg + (size_t)bh * HDIM * NN;
    const int j0 = w * 1024;
    const int fr = l & 15, kf = (l >> 4) * 8;

    f32x4 acc[5][4];
    #pragma unroll
    for (int m = 0; m < 5; ++m)
        #pragma unroll
        for (int n = 0; n < 4; ++n) acc[m][n] = (f32x4){0.f, 0.f, 0.f, 0.f};
    short8 ones;
    #pragma unroll
    for (int i = 0; i < 8; ++i) ones[i] = (short)0x3F80;

    for (int js = 0; js < 1024; js += 32) {
        const int jb = j0 + js + kf;
        short8 a[4], b[4];
        #pragma unroll
        for (int m = 0; m < 4; ++m)
            a[m] = *reinterpret_cast<const short8*>(&vb[(size_t)(m * 16 + fr) * NN + jb]);
        #pragma unroll
        for (int n = 0; n < 4; ++n)
            b[n] = *reinterpret_cast<const short8*>(&kb[(size_t)(n * 16 + fr) * NN + jb]);
        #pragma unroll
        for (int m = 0; m < 4; ++m)
            #pragma unroll
            for (int n = 0; n < 4; ++n)
                acc[m][n] = __builtin_amdgcn_mfma_f32_16x16x32_bf16(a[m], b[n], acc[m][n], 0, 0, 0);
        #pragma unroll
        for (int n = 0; n < 4; ++n)
            acc[4][n] = __builtin_amdgcn_mfma_f32_16x16x32_bf16(ones, b[n], acc[4][n], 0, 0, 0);
    }
    #pragma unroll
    for (int m = 0; m < 5; ++m)
        #pragma unroll
        for (int n = 0; n < 4; ++n)
            #pragma unroll
            for (int j = 0; j < 4; ++j)
                red[w][(m * 16 + (l >> 4) * 4 + j) * 64 + fr + n * 16] = acc[m][n][j];
    __syncthreads();
    u16* base = kvt + bh * 5120;
    for (int i = t; i < 5120; i += 256)
        base[i] = f2b(red[0][i] + red[1][i] + red[2][i] + red[3][i]);
}

// ---------------- K4: MFMA attention finish + depthwise conv (coalesced v_b) ------------
__global__ __launch_bounds__(256) void k_attn_mfma(
    const u16* __restrict__ q, const u16* __restrict__ v,
    const u16* __restrict__ kvt,
    const float* __restrict__ dwc_w, const float* __restrict__ dwc_b,
    u16* __restrict__ out2)
{
    __shared__ u16 att[4][64 * 68];
    const int t = threadIdx.x;
    const int l = t & 63, w = t >> 6;
    const int bh = blockIdx.x;
    const int tb = blockIdx.y * 256 + w * 64;
    const size_t hb = (size_t)bh * NN * HDIM;
    const u16* qb  = q + hb + (size_t)tb * HDIM;
    const u16* kvb = kvt + bh * 5120;

    const int fr = l & 15;
    const int kfrag = (l >> 4) * 8;

    short8 bfr[5][2];
    #pragma unroll
    for (int n = 0; n < 5; ++n)
        #pragma unroll
        for (int ks = 0; ks < 2; ++ks)
            bfr[n][ks] = *reinterpret_cast<const short8*>(&kvb[(n * 16 + fr) * 64 + ks * 32 + kfrag]);

    f32x4 acc[4][5];
    #pragma unroll
    for (int m = 0; m < 4; ++m)
        #pragma unroll
        for (int n = 0; n < 5; ++n) acc[m][n] = (f32x4){0.f, 0.f, 0.f, 0.f};

    #pragma unroll
    for (int m = 0; m < 4; ++m)
        #pragma unroll
        for (int ks = 0; ks < 2; ++ks) {
            short8 a = *reinterpret_cast<const short8*>(&qb[(m * 16 + fr) * 64 + ks * 32 + kfrag]);
            #pragma unroll
            for (int n = 0; n < 5; ++n)
                acc[m][n] = __builtin_amdgcn_mfma_f32_16x16x32_bf16(a, bfr[n][ks], acc[m][n], 0, 0, 0);
        }

    #pragma unroll
    for (int m = 0; m < 4; ++m)
        #pragma unroll
        for (int j = 0; j < 4; ++j) {
            const float den = __shfl(acc[m][4][j], l & 48);
            const float z = 1.f / (den + 1e-6f);
            const int row = m * 16 + (l >> 4) * 4 + j;
            #pragma unroll
            for (int n = 0; n < 4; ++n)
                att[w][row * 68 + fr + n * 16] = f2b(acc[m][n][j] * z);
        }
    __syncthreads();

    const int d = l;
    float w5[5];
    #pragma unroll
    for (int dh = 0; dh < 5; ++dh) w5[dh] = dwc_w[d * 25 + dh * 5 + 2];
    const float cbias = dwc_b[d];
    const int b_ = bh >> 4, h_ = bh & 15;
    u16* obase = out2 + (size_t)b_ * NN * CDIM + (size_t)h_ * 64 + d;
    float win[5];
    #pragma unroll
    for (int p = 0; p < 4; ++p) {
        const int src = tb - 2 + p;
        win[p] = (src >= 0 && src < NN) ? b2f(v[hb + (size_t)src * 64 + d]) : 0.f;
    }
    for (int it = 0; it < 64; ++it) {
        const int srcn = tb + it + 2;
        win[4] = (srcn < NN) ? b2f(v[hb + (size_t)srcn * 64 + d]) : 0.f;
        const float fm = cbias + w5[0] * win[0] + w5[1] * win[1] + w5[2] * win[2]
                               + w5[3] * win[3] + w5[4] * win[4];
        const float attn = b2f((short)att[w][it * 68 + d]);
        obase[(size_t)(tb + it) * CDIM] = f2b(attn + fm);
        win[0] = win[1]; win[1] = win[2]; win[2] = win[3]; win[3] = win[4];
    }
}

extern "C" void kernel_launch(void* const* d_in, const int* in_sizes, int n_in,
                              void* d_out, int out_size, void* d_ws, size_t ws_size,
                              hipStream_t stream)
{
    const float* x       = (const float*)d_in[0];
    const float* qkv_w   = (const float*)d_in[1];
    const float* qkv_b   = (const float*)d_in[2];
    const float* proj_w  = (const float*)d_in[3];
    const float* proj_b  = (const float*)d_in[4];
    const float* pos_enc = (const float*)d_in[5];
    const float* dwc_w   = (const float*)d_in[6];
    const float* dwc_b   = (const float*)d_in[7];

    const size_t QKV = 16777216;
    char* p = (char*)d_ws;
    u16* q_b    = (u16*)p;               p += QKV * 2;
    u16* ktg    = (u16*)p;               p += QKV * 2;  // reused as out2 after K2
    u16* v_b    = (u16*)p;               p += QKV * 2;
    u16* vtg    = (u16*)p;               p += QKV * 2;
    u16* x_b    = (u16*)p;               p += QKV * 2;
    u16* qkvw_b = (u16*)p;               p += (size_t)3145728 * 2;
    u16* projw_b= (u16*)p;               p += (size_t)1048576 * 2;
    u16* kvt    = (u16*)p;               p += (size_t)(BH * 5120) * 2;
    const size_t need_bytes = (size_t)(p - (char*)d_ws);

    if (ws_size < need_bytes) {
        const float diag = 4096.0f + (float)(ws_size >> 20);
        k_fill_diag<<<(out_size + 255) / 256, 256, 0, stream>>>((float*)d_out, out_size, diag);
        return;
    }

    u16* out2 = ktg;            // ktg dead after k_kv_fused
    float* out = (float*)d_out;

    k_convert_all<<<20480, 256, 0, stream>>>(x, qkv_w, proj_w, x_b, qkvw_b, projw_b);

    k_gemm1_256 <<<dim3(12, 64), 512, 0, stream>>>(x_b, qkvw_b, qkv_b, pos_enc, q_b, ktg, v_b, vtg);
    k_kv_fused  <<<64,           256, 0, stream>>>(ktg, vtg, kvt);
    k_attn_mfma <<<dim3(64, 16), 256, 0, stream>>>(q_b, v_b, kvt, dwc_w, dwc_b, out2);
    k_gemm2_256 <<<dim3(4, 64),  512, 0, stream>>>(out2, projw_b, proj_b, out);
}

// Round 13
// 420.177 us; speedup vs baseline: 4.3965x; 4.3965x over previous
//
#include <hip/hip_runtime.h>

// SLabLinearAttention: B=4 N=4096 C=1024 H=16 HD=64 KH=5
// Round 13: TLP experiment done right. GEMM tile 128x256 (per-wave 64x64, acc=64 VGPR,
// total ~115) + 48KB LDS dbuf -> genuinely 2 blocks/CU without spill (R12 spilled:
// launch_bounds(512,4) + 128-VGPR acc). De-fenced 2-barrier loop (R10) kept.
// launch_bounds(512,3) = allocator headroom, no forced spill. kv_fused kept.

#define BB   4
#define NN   4096
#define CDIM 1024
#define NH   16
#define HDIM 64
#define BH   64

typedef __attribute__((ext_vector_type(8))) short short8;
typedef __attribute__((ext_vector_type(4))) float f32x4;
typedef unsigned short u16;

__device__ __forceinline__ float b2f(short s) {
    union { unsigned u; float f; } c;
    c.u = ((unsigned)(unsigned short)s) << 16;
    return c.f;
}
__device__ __forceinline__ u16 f2b(float f) {   // RNE
    unsigned u = __float_as_uint(f);
    return (u16)((u + 0x7fffu + ((u >> 16) & 1u)) >> 16);
}
__device__ __forceinline__ void gload16(const void* g, void* l) {
    __builtin_amdgcn_global_load_lds((const __attribute__((address_space(1))) void*)g,
                                     (__attribute__((address_space(3))) void*)l, 16, 0, 0);
}

__global__ __launch_bounds__(256) void k_fill_diag(float* __restrict__ out, int n, float val)
{
    int i = blockIdx.x * 256 + threadIdx.x;
    if (i < n) out[i] = val;
}

// fused convert: x (4194304 f4) | qkv_w (786432 f4) | proj_w (262144 f4)
__global__ __launch_bounds__(256) void k_convert_all(
    const float* __restrict__ x, const float* __restrict__ qw, const float* __restrict__ pw,
    u16* __restrict__ xb, u16* __restrict__ qwb, u16* __restrict__ pwb)
{
    int i = blockIdx.x * 256 + threadIdx.x;
    const float* src; u16* dst; int j;
    if (i < 4194304)      { src = x;  dst = xb;  j = i; }
    else if (i < 4980736) { src = qw; dst = qwb; j = i - 4194304; }
    else                  { src = pw; dst = pwb; j = i - 4980736; }
    float4 v = reinterpret_cast<const float4*>(src)[j];
    ushort4 o;
    o.x = f2b(v.x); o.y = f2b(v.y); o.z = f2b(v.z); o.w = f2b(v.w);
    reinterpret_cast<ushort4*>(dst)[j] = o;
}

// ======= de-fenced 2-barrier 128x256 BK=32 GEMM core (48KB LDS, 2 blk/CU) =======
// LDS (u16): buf b @ b*12288 elems; A (128x32, 4096 el) @ +0, B (256x32, 8192 el) @ +4096.
// phys chunk = chunk ^ ((row>>1)&3); pre-swizzled global src (qa), swizzled ds_read (physE).
// STG = 3 gload16/thread (1 A + 2 B). Ledger: iter kt reads buf[kt&1]; barrier (a) after
// MFMA retires reads; STG(kt+2) overwrites buf[kt&1]; vmcnt(3) at boundary => only
// kt+2's 3 loads outstanding => kt+1 landed; barrier (b) publishes.
#define GEMM128x256()                                                                    \
    const int t = threadIdx.x;                                                           \
    const int l = t & 63, w = t >> 6;                                                    \
    const int wr = w >> 2, wc = w & 3;                                                   \
    const int fr = l & 15;                                                               \
    const int physE  = ((l >> 4) ^ ((fr >> 1) & 3)) * 8;                                 \
    const int qa     = ((t & 3) ^ ((t >> 3) & 3)) * 8;                                   \
    const int sRow   = t >> 2;                         /* 0..127 */                      \
    const u16* gA0 = A  + (size_t)(brow + sRow) * 1024 + qa;                             \
    const u16* gB0 = Bw + (size_t)(bcol + sRow) * 1024 + qa;                             \
    char* ldsc = (char*)lds;                                                             \
    const int afBase = (wr * 64 + fr) * 32 + physE;                                      \
    const int bfBase = 4096 + (wc * 64 + fr) * 32 + physE;                               \
    f32x4 acc[4][4];                                                                     \
    _Pragma("unroll")                                                                    \
    for (int m = 0; m < 4; ++m)                                                          \
        _Pragma("unroll")                                                                \
        for (int n = 0; n < 4; ++n) acc[m][n] = (f32x4){0.f, 0.f, 0.f, 0.f};             \
    auto STG = [&](int kt) {                                                             \
        const u16* ga = gA0 + kt * 32;                                                   \
        const u16* gb = gB0 + kt * 32;                                                   \
        char* d = ldsc + (kt & 1) * 24576 + t * 16;                                      \
        gload16(ga,          d);              /* A rows 0..127            */             \
        gload16(gb,          d + 8192);       /* B rows 0..127            */             \
        gload16(gb + 131072, d + 16384);      /* B rows 128..255          */             \
    };                                                                                   \
    STG(0); STG(1);                                                                      \
    asm volatile("s_waitcnt vmcnt(3)" ::: "memory");                                     \
    __builtin_amdgcn_s_barrier();                                                        \
    _Pragma("unroll 1")                                                                  \
    for (int kt = 0; kt < 32; ++kt) {                                                    \
        const int B0 = (kt & 1) * 12288;                                                 \
        short8 af[4], bf[4];                                                             \
        _Pragma("unroll")                                                                \
        for (int n = 0; n < 4; ++n)                                                      \
            bf[n] = *reinterpret_cast<const short8*>(&lds[B0 + bfBase + n * 512]);       \
        _Pragma("unroll")                                                                \
        for (int m = 0; m < 4; ++m)                                                      \
            af[m] = *reinterpret_cast<const short8*>(&lds[B0 + afBase + m * 512]);       \
        __builtin_amdgcn_s_setprio(1);                                                   \
        _Pragma("unroll")                                                                \
        for (int m = 0; m < 4; ++m)                                                      \
            _Pragma("unroll")                                                            \
            for (int n = 0; n < 4; ++n)                                                  \
                acc[m][n] = __builtin_amdgcn_mfma_f32_16x16x32_bf16(af[m], bf[n], acc[m][n], 0, 0, 0); \
        __builtin_amdgcn_s_setprio(0);                                                   \
        __builtin_amdgcn_s_barrier();   /* (a) reads of buf[kt&1] retired */             \
        if (kt + 2 < 32) STG(kt + 2);                                                    \
        if (kt < 30) { asm volatile("s_waitcnt vmcnt(3)" ::: "memory"); }                \
        else         { asm volatile("s_waitcnt vmcnt(0)" ::: "memory"); }                \
        __builtin_amdgcn_s_barrier();   /* (b) tile kt+1 published */                    \
    }

// ---------------- GEMM1: [16384,3072] = x @ qkv_w^T, 64-row half-pass epilogue ---------
// Outputs: q_b[bh][j][d], v_b[bh][j][d] (row-major); ktg[bh][c][j], vtg[bh][d][j].
__global__ __launch_bounds__(512, 3) void k_gemm1_128(
    const u16* __restrict__ A, const u16* __restrict__ Bw,
    const float* __restrict__ bias, const float* __restrict__ pos_enc,
    u16* __restrict__ q, u16* __restrict__ ktg, u16* __restrict__ v, u16* __restrict__ vtg)
{
    __shared__ u16 lds[24576];   // 48KB: K-loop dbuf, then 64x256 u16 C-half
    // bijective XCD swizzle: nwg = 12*128 = 1536, %8==0
    const int lid = blockIdx.y * 12 + blockIdx.x;
    const int swz = (lid & 7) * 192 + (lid >> 3);
    const int bcol = (swz % 12) * 256;
    const int brow = (swz / 12) * 128;

    GEMM128x256()

    const int part = bcol >> 10;                 // 0=q 1=k 2=v, uniform per block
    const int b_ = brow >> 12;
    #pragma unroll 1
    for (int half = 0; half < 2; ++half) {
        __syncthreads();
        if (wr == half) {
            const int row_l = (l >> 4) * 4;
            const int col_l = wc * 64 + fr;
            #pragma unroll
            for (int n = 0; n < 4; ++n) {
                const int col = col_l + n * 16;
                const int gc = bcol + col;
                const int c = gc & 1023;
                float bv = bias[gc];
                if (part == 1) bv += pos_enc[c];
                const int cc = col >> 3, in = col & 7;
                #pragma unroll
                for (int m = 0; m < 4; ++m)
                    #pragma unroll
                    for (int j = 0; j < 4; ++j) {
                        const int row = m * 16 + row_l + j;          // 0..63
                        float val = acc[m][n][j] + bv;
                        if (part != 2) val = fmaxf(val, 0.f);
                        lds[row * 256 + ((cc ^ (row & 7)) << 3) + in] = f2b(val);
                    }
            }
        }
        __syncthreads();
        const int i0 = (brow & 4095) + half * 64;
        if (part != 1) {
            u16* dst = (part == 0) ? q : v;
            #pragma unroll
            for (int it = 0; it < 4; ++it) {
                const int id = it * 512 + t;                 // 0..2047
                const int row = id >> 5, cc = id & 31;
                short8 val = *reinterpret_cast<const short8*>(&lds[row * 256 + ((cc ^ (row & 7)) << 3)]);
                const int c2 = (bcol + cc * 8) & 1023;
                const int h2 = c2 >> 6, d2 = c2 & 63;
                *reinterpret_cast<short8*>(
                    &dst[((size_t)(b_ * NH + h2) * NN + i0 + row) * HDIM + d2]) = val;
            }
        }
        if (part != 0) {
            u16* dstT = (part == 1) ? ktg : vtg;
            #pragma unroll
            for (int it = 0; it < 4; ++it) {
                const int id = it * 512 + t;                 // 0..2047
                const int cl = id & 255, jc = id >> 8;       // c-local, j-chunk (8 rows, jc<8)
                short8 vv;
                #pragma unroll
                for (int rr = 0; rr < 8; ++rr)
                    vv[rr] = (short)lds[(jc * 8 + rr) * 256 + (((cl >> 3) ^ rr) << 3) + (cl & 7)];
                const int c2 = (bcol + cl) & 1023;
                const int h2 = c2 >> 6, d2 = c2 & 63;
                *reinterpret_cast<short8*>(
                    &dstT[((size_t)(b_ * NH + h2) * HDIM + d2) * NN + i0 + jc * 8]) = vv;
            }
        }
    }
}

// ---------------- GEMM2: [16384,1024] = out2 @ proj_w^T + b, 32-row quarter-pass -------
__global__ __launch_bounds__(512, 3) void k_gemm2_128(
    const u16* __restrict__ A, const u16* __restrict__ Bw,
    const float* __restrict__ bias, float* __restrict__ out)
{
    __shared__ u16 lds[24576];   // 48KB: K-loop dbuf, then 32x256 fp32 C-quarter
    // bijective XCD swizzle: nwg = 4*128 = 512, %8==0
    const int lid = blockIdx.y * 4 + blockIdx.x;
    const int swz = (lid & 7) * 64 + (lid >> 3);
    const int bcol = (swz % 4) * 256;
    const int brow = (swz / 4) * 128;

    GEMM128x256()

    float* ldsf = reinterpret_cast<float*>(lds);     // 32 rows x 256 f32 = 32KB
    #pragma unroll 1
    for (int qp = 0; qp < 4; ++qp) {
        __syncthreads();
        if (wr == (qp >> 1)) {
            const int m0 = (qp & 1) * 2;
            const int row_l = (l >> 4) * 4;
            const int col_l = wc * 64 + fr;
            #pragma unroll
            for (int n = 0; n < 4; ++n) {
                const int col = col_l + n * 16;
                const float bv = bias[bcol + col];
                #pragma unroll
                for (int mm = 0; mm < 2; ++mm)
                    #pragma unroll
                    for (int j = 0; j < 4; ++j) {
                        const int row = mm * 16 + row_l + j;     // 0..31
                        ldsf[row * 256 + (col ^ (((row >> 2) & 3) << 3))] = acc[m0 + mm][n][j] + bv;
                    }
            }
        }
        __syncthreads();
        const float4* ldsf4 = reinterpret_cast<const float4*>(ldsf);
        #pragma unroll
        for (int it = 0; it < 4; ++it) {
            const int id = it * 512 + t;                 // 0..2047
            const int row = id >> 6, cc4 = id & 63;      // row 0..31
            float4 vv = ldsf4[row * 64 + (cc4 ^ (((row >> 2) & 3) << 1))];
            *reinterpret_cast<float4*>(
                &out[(size_t)(brow + qp * 32 + row) * CDIM + bcol + cc4 * 4]) = vv;
        }
    }
}

// ---------------- K2: fused kv via MFMA + in-LDS reduction -> kvt bf16 ----------------
__global__ __launch_bounds__(256) void k_kv_fused(
    const u16* __restrict__ ktg, const u16* __restrict__ vtg,
    u16* __restrict__ kvt)
{
    __shared__ float red[4][5120];   // 80 KB
    const int t = threadIdx.x, l = t & 63, w = t >> 6;
    const int bh = blockIdx.x;
    const u16* kb = ktg + (size_t)bh * HDIM * NN;
    const u16* vb = vtg + (size_t)bh * HDIM * NN;
    const int j0 = w * 1024;
    const int fr = l & 15, kf = (l >> 4) * 8;

    f32x4 acc[5][4];
    #pragma unroll
    for (int m = 0; m < 5; ++m)
        #pragma unroll
        for (int n = 0; n < 4; ++n) acc[m][n] = (f32x4){0.f, 0.f, 0.f, 0.f};
    short8 ones;
    #pragma unroll
    for (int i = 0; i < 8; ++i) ones[i] = (short)0x3F80;

    for (int js = 0; js < 1024; js += 32) {
        const int jb = j0 + js + kf;
        short8 a[4], b[4];
        #pragma unroll
        for (int m = 0; m < 4; ++m)
            a[m] = *reinterpret_cast<const short8*>(&vb[(size_t)(m * 16 + fr) * NN + jb]);
        #pragma unroll
        for (int n = 0; n < 4; ++n)
            b[n] = *reinterpret_cast<const short8*>(&kb[(size_t)(n * 16 + fr) * NN + jb]);
        #pragma unroll
        for (int m = 0; m < 4; ++m)
            #pragma unroll
            for (int n = 0; n < 4; ++n)
                acc[m][n] = __builtin_amdgcn_mfma_f32_16x16x32_bf16(a[m], b[n], acc[m][n], 0, 0, 0);
        #pragma unroll
        for (int n = 0; n < 4; ++n)
            acc[4][n] = __builtin_amdgcn_mfma_f32_16x16x32_bf16(ones, b[n], acc[4][n], 0, 0, 0);
    }
    #pragma unroll
    for (int m = 0; m < 5; ++m)
        #pragma unroll
        for (int n = 0; n < 4; ++n)
            #pragma unroll
            for (int j = 0; j < 4; ++j)
                red[w][(m * 16 + (l >> 4) * 4 + j) * 64 + fr + n * 16] = acc[m][n][j];
    __syncthreads();
    u16* base = kvt + bh * 5120;
    for (int i = t; i < 5120; i += 256)
        base[i] = f2b(red[0][i] + red[1][i] + red[2][i] + red[3][i]);
}

// ---------------- K4: MFMA attention finish + depthwise conv (coalesced v_b) ------------
__global__ __launch_bounds__(256) void k_attn_mfma(
    const u16* __restrict__ q, const u16* __restrict__ v,
    const u16* __restrict__ kvt,
    const float* __restrict__ dwc_w, const float* __restrict__ dwc_b,
    u16* __restrict__ out2)
{
    __shared__ u16 att[4][64 * 68];
    const int t = threadIdx.x;
    const int l = t & 63, w = t >> 6;
    const int bh = blockIdx.x;
    const int tb = blockIdx.y * 256 + w * 64;
    const size_t hb = (size_t)bh * NN * HDIM;
    const u16* qb  = q + hb + (size_t)tb * HDIM;
    const u16* kvb = kvt + bh * 5120;

    const int fr = l & 15;
    const int kfrag = (l >> 4) * 8;

    short8 bfr[5][2];
    #pragma unroll
    for (int n = 0; n < 5; ++n)
        #pragma unroll
        for (int ks = 0; ks < 2; ++ks)
            bfr[n][ks] = *reinterpret_cast<const short8*>(&kvb[(n * 16 + fr) * 64 + ks * 32 + kfrag]);

    f32x4 acc[4][5];
    #pragma unroll
    for (int m = 0; m < 4; ++m)
        #pragma unroll
        for (int n = 0; n < 5; ++n) acc[m][n] = (f32x4){0.f, 0.f, 0.f, 0.f};

    #pragma unroll
    for (int m = 0; m < 4; ++m)
        #pragma unroll
        for (int ks = 0; ks < 2; ++ks) {
            short8 a = *reinterpret_cast<const short8*>(&qb[(m * 16 + fr) * 64 + ks * 32 + kfrag]);
            #pragma unroll
            for (int n = 0; n < 5; ++n)
                acc[m][n] = __builtin_amdgcn_mfma_f32_16x16x32_bf16(a, bfr[n][ks], acc[m][n], 0, 0, 0);
        }

    #pragma unroll
    for (int m = 0; m < 4; ++m)
        #pragma unroll
        for (int j = 0; j < 4; ++j) {
            const float den = __shfl(acc[m][4][j], l & 48);
            const float z = 1.f / (den + 1e-6f);
            const int row = m * 16 + (l >> 4) * 4 + j;
            #pragma unroll
            for (int n = 0; n < 4; ++n)
                att[w][row * 68 + fr + n * 16] = f2b(acc[m][n][j] * z);
        }
    __syncthreads();

    const int d = l;
    float w5[5];
    #pragma unroll
    for (int dh = 0; dh < 5; ++dh) w5[dh] = dwc_w[d * 25 + dh * 5 + 2];
    const float cbias = dwc_b[d];
    const int b_ = bh >> 4, h_ = bh & 15;
    u16* obase = out2 + (size_t)b_ * NN * CDIM + (size_t)h_ * 64 + d;
    float win[5];
    #pragma unroll
    for (int p = 0; p < 4; ++p) {
        const int src = tb - 2 + p;
        win[p] = (src >= 0 && src < NN) ? b2f(v[hb + (size_t)src * 64 + d]) : 0.f;
    }
    for (int it = 0; it < 64; ++it) {
        const int srcn = tb + it + 2;
        win[4] = (srcn < NN) ? b2f(v[hb + (size_t)srcn * 64 + d]) : 0.f;
        const float fm = cbias + w5[0] * win[0] + w5[1] * win[1] + w5[2] * win[2]
                               + w5[3] * win[3] + w5[4] * win[4];
        const float attn = b2f((short)att[w][it * 68 + d]);
        obase[(size_t)(tb + it) * CDIM] = f2b(attn + fm);
        win[0] = win[1]; win[1] = win[2]; win[2] = win[3]; win[3] = win[4];
    }
}

extern "C" void kernel_launch(void* const* d_in, const int* in_sizes, int n_in,
                              void* d_out, int out_size, void* d_ws, size_t ws_size,
                              hipStream_t stream)
{
    const float* x       = (const float*)d_in[0];
    const float* qkv_w   = (const float*)d_in[1];
    const float* qkv_b   = (const float*)d_in[2];
    const float* proj_w  = (const float*)d_in[3];
    const float* proj_b  = (const float*)d_in[4];
    const float* pos_enc = (const float*)d_in[5];
    const float* dwc_w   = (const float*)d_in[6];
    const float* dwc_b   = (const float*)d_in[7];

    const size_t QKV = 16777216;
    char* p = (char*)d_ws;
    u16* q_b    = (u16*)p;               p += QKV * 2;
    u16* ktg    = (u16*)p;               p += QKV * 2;  // reused as out2 after K2
    u16* v_b    = (u16*)p;               p += QKV * 2;
    u16* vtg    = (u16*)p;               p += QKV * 2;
    u16* x_b    = (u16*)p;               p += QKV * 2;
    u16* qkvw_b = (u16*)p;               p += (size_t)3145728 * 2;
    u16* projw_b= (u16*)p;               p += (size_t)1048576 * 2;
    u16* kvt    = (u16*)p;               p += (size_t)(BH * 5120) * 2;
    const size_t need_bytes = (size_t)(p - (char*)d_ws);

    if (ws_size < need_bytes) {
        const float diag = 4096.0f + (float)(ws_size >> 20);
        k_fill_diag<<<(out_size + 255) / 256, 256, 0, stream>>>((float*)d_out, out_size, diag);
        return;
    }

    u16* out2 = ktg;            // ktg dead after k_kv_fused
    float* out = (float*)d_out;

    k_convert_all<<<20480, 256, 0, stream>>>(x, qkv_w, proj_w, x_b, qkvw_b, projw_b);

    k_gemm1_128 <<<dim3(12, 128), 512, 0, stream>>>(x_b, qkvw_b, qkv_b, pos_enc, q_b, ktg, v_b, vtg);
    k_kv_fused  <<<64,            256, 0, stream>>>(ktg, vtg, kvt);
    k_attn_mfma <<<dim3(64, 16),  256, 0, stream>>>(q_b, v_b, kvt, dwc_w, dwc_b, out2);
    k_gemm2_128 <<<dim3(4, 128),  512, 0, stream>>>(out2, projw_b, proj_b, out);
}

// Round 14
// 312.300 us; speedup vs baseline: 5.9152x; 1.3454x over previous
//
#include <hip/hip_runtime.h>

// SLabLinearAttention: B=4 N=4096 C=1024 H=16 HD=64 KH=5
// Round 14: revert to R10 (best, 276.6us) + single delta: gemm2 at 128x256 tile
// (2 blk/CU; B=2MB L2-resident so no R13-style fetch penalty; A fetch invariant).
// gemm1/kv/attn/convert are R10 verbatim.

#define BB   4
#define NN   4096
#define CDIM 1024
#define NH   16
#define HDIM 64
#define BH   64

typedef __attribute__((ext_vector_type(8))) short short8;
typedef __attribute__((ext_vector_type(4))) float f32x4;
typedef unsigned short u16;

__device__ __forceinline__ float b2f(short s) {
    union { unsigned u; float f; } c;
    c.u = ((unsigned)(unsigned short)s) << 16;
    return c.f;
}
__device__ __forceinline__ u16 f2b(float f) {   // RNE
    unsigned u = __float_as_uint(f);
    return (u16)((u + 0x7fffu + ((u >> 16) & 1u)) >> 16);
}
__device__ __forceinline__ void gload16(const void* g, void* l) {
    __builtin_amdgcn_global_load_lds((const __attribute__((address_space(1))) void*)g,
                                     (__attribute__((address_space(3))) void*)l, 16, 0, 0);
}

__global__ __launch_bounds__(256) void k_fill_diag(float* __restrict__ out, int n, float val)
{
    int i = blockIdx.x * 256 + threadIdx.x;
    if (i < n) out[i] = val;
}

// fused convert: x (4194304 f4) | qkv_w (786432 f4) | proj_w (262144 f4)
__global__ __launch_bounds__(256) void k_convert_all(
    const float* __restrict__ x, const float* __restrict__ qw, const float* __restrict__ pw,
    u16* __restrict__ xb, u16* __restrict__ qwb, u16* __restrict__ pwb)
{
    int i = blockIdx.x * 256 + threadIdx.x;
    const float* src; u16* dst; int j;
    if (i < 4194304)      { src = x;  dst = xb;  j = i; }
    else if (i < 4980736) { src = qw; dst = qwb; j = i - 4194304; }
    else                  { src = pw; dst = pwb; j = i - 4980736; }
    float4 v = reinterpret_cast<const float4*>(src)[j];
    ushort4 o;
    o.x = f2b(v.x); o.y = f2b(v.y); o.z = f2b(v.z); o.w = f2b(v.w);
    reinterpret_cast<ushort4*>(dst)[j] = o;
}

// ======= de-fenced 2-barrier 256x256 BK=64 GEMM core (R10 verbatim) =======
#define GEMM256_2BAR()                                                                   \
    const int t = threadIdx.x;                                                           \
    const int l = t & 63, w = t >> 6;                                                    \
    const int wr = w >> 2, wc = w & 3;                                                   \
    const int fr = l & 15;                                                               \
    const int physE  = ((l >> 4) ^ ((fr >> 1) & 3)) * 8;                                 \
    const int qa     = ((l & 3) ^ ((l >> 3) & 3)) * 8;                                   \
    const int aRow   = w * 16 + (l >> 2);                                                \
    const u16* gA0 = A  + (size_t)(brow + aRow) * 1024 + qa;                             \
    const u16* gB0 = Bw + (size_t)(bcol + aRow) * 1024 + qa;                             \
    char* ldsc = (char*)lds;                                                             \
    const int afBase = (wr * 128 + fr) * 32 + physE;                                     \
    const int bfBase = 16384 + (wc * 64 + fr) * 32 + physE;                              \
    f32x4 acc[8][4];                                                                     \
    _Pragma("unroll")                                                                    \
    for (int m = 0; m < 8; ++m)                                                          \
        _Pragma("unroll")                                                                \
        for (int n = 0; n < 4; ++n) acc[m][n] = (f32x4){0.f, 0.f, 0.f, 0.f};             \
    auto STG = [&](int kt, int kh, int isB) {                                            \
        const u16* g = (isB ? gB0 : gA0) + kt * 64 + kh * 32;                            \
        char* d = ldsc + (kt & 1) * 65536 + isB * 32768 + kh * 16384 + w * 1024 + l * 16;\
        gload16(g,          d);                                                          \
        gload16(g + 131072, d + 8192);                                                   \
    };                                                                                   \
    STG(0,0,0); STG(0,0,1); STG(0,1,0); STG(0,1,1); STG(1,0,0); STG(1,0,1);              \
    asm volatile("s_waitcnt vmcnt(4)" ::: "memory");                                     \
    __builtin_amdgcn_s_barrier();                                                        \
    _Pragma("unroll 1")                                                                  \
    for (int kt = 0; kt < 16; ++kt) {                                                    \
        const int B0 = (kt & 1) * 32768;                                                 \
        short8 af[8], bf[4];                                                             \
        /* ---- phase A: kh0 ---- */                                                     \
        _Pragma("unroll")                                                                \
        for (int n = 0; n < 4; ++n)                                                      \
            bf[n] = *reinterpret_cast<const short8*>(&lds[B0 + bfBase + n * 512]);       \
        _Pragma("unroll")                                                                \
        for (int m = 0; m < 8; ++m)                                                      \
            af[m] = *reinterpret_cast<const short8*>(&lds[B0 + afBase + m * 512]);       \
        if (kt + 1 < 16) { STG(kt + 1, 1, 0); STG(kt + 1, 1, 1); }                       \
        __builtin_amdgcn_s_setprio(1);                                                   \
        _Pragma("unroll")                                                                \
        for (int m = 0; m < 8; ++m)                                                      \
            _Pragma("unroll")                                                            \
            for (int n = 0; n < 4; ++n)                                                  \
                acc[m][n] = __builtin_amdgcn_mfma_f32_16x16x32_bf16(af[m], bf[n], acc[m][n], 0, 0, 0); \
        __builtin_amdgcn_s_setprio(0);                                                   \
        __builtin_amdgcn_s_barrier();   /* (a) kh0 reads retired before overwrite */     \
        /* ---- phase B: kh1 ---- */                                                     \
        _Pragma("unroll")                                                                \
        for (int n = 0; n < 4; ++n)                                                      \
            bf[n] = *reinterpret_cast<const short8*>(&lds[B0 + 8192 + bfBase + n * 512]);\
        _Pragma("unroll")                                                                \
        for (int m = 0; m < 8; ++m)                                                      \
            af[m] = *reinterpret_cast<const short8*>(&lds[B0 + 8192 + afBase + m * 512]);\
        if (kt + 2 < 16) { STG(kt + 2, 0, 0); STG(kt + 2, 0, 1); }                       \
        __builtin_amdgcn_s_setprio(1);                                                   \
        _Pragma("unroll")                                                                \
        for (int m = 0; m < 8; ++m)                                                      \
            _Pragma("unroll")                                                            \
            for (int n = 0; n < 4; ++n)                                                  \
                acc[m][n] = __builtin_amdgcn_mfma_f32_16x16x32_bf16(af[m], bf[n], acc[m][n], 0, 0, 0); \
        __builtin_amdgcn_s_setprio(0);                                                   \
        if (kt < 15) { asm volatile("s_waitcnt vmcnt(4)" ::: "memory"); }                \
        else         { asm volatile("s_waitcnt vmcnt(0)" ::: "memory"); }                \
        __builtin_amdgcn_s_barrier();   /* (b) staged tile kt+1 published */             \
    }

// ======= 128x256 BK=32 core (for gemm2 only; 48KB LDS, 2 blk/CU) =======
#define GEMM128x256()                                                                    \
    const int t = threadIdx.x;                                                           \
    const int l = t & 63, w = t >> 6;                                                    \
    const int wr = w >> 2, wc = w & 3;                                                   \
    const int fr = l & 15;                                                               \
    const int physE  = ((l >> 4) ^ ((fr >> 1) & 3)) * 8;                                 \
    const int qa     = ((t & 3) ^ ((t >> 3) & 3)) * 8;                                   \
    const int sRow   = t >> 2;                                                           \
    const u16* gA0 = A  + (size_t)(brow + sRow) * 1024 + qa;                             \
    const u16* gB0 = Bw + (size_t)(bcol + sRow) * 1024 + qa;                             \
    char* ldsc = (char*)lds;                                                             \
    const int afBase = (wr * 64 + fr) * 32 + physE;                                      \
    const int bfBase = 4096 + (wc * 64 + fr) * 32 + physE;                               \
    f32x4 acc[4][4];                                                                     \
    _Pragma("unroll")                                                                    \
    for (int m = 0; m < 4; ++m)                                                          \
        _Pragma("unroll")                                                                \
        for (int n = 0; n < 4; ++n) acc[m][n] = (f32x4){0.f, 0.f, 0.f, 0.f};             \
    auto STG = [&](int kt) {                                                             \
        const u16* ga = gA0 + kt * 32;                                                   \
        const u16* gb = gB0 + kt * 32;                                                   \
        char* d = ldsc + (kt & 1) * 24576 + t * 16;                                      \
        gload16(ga,          d);                                                         \
        gload16(gb,          d + 8192);                                                  \
        gload16(gb + 131072, d + 16384);                                                 \
    };                                                                                   \
    STG(0); STG(1);                                                                      \
    asm volatile("s_waitcnt vmcnt(3)" ::: "memory");                                     \
    __builtin_amdgcn_s_barrier();                                                        \
    _Pragma("unroll 1")                                                                  \
    for (int kt = 0; kt < 32; ++kt) {                                                    \
        const int B0 = (kt & 1) * 12288;                                                 \
        short8 af[4], bf[4];                                                             \
        _Pragma("unroll")                                                                \
        for (int n = 0; n < 4; ++n)                                                      \
            bf[n] = *reinterpret_cast<const short8*>(&lds[B0 + bfBase + n * 512]);       \
        _Pragma("unroll")                                                                \
        for (int m = 0; m < 4; ++m)                                                      \
            af[m] = *reinterpret_cast<const short8*>(&lds[B0 + afBase + m * 512]);       \
        __builtin_amdgcn_s_setprio(1);                                                   \
        _Pragma("unroll")                                                                \
        for (int m = 0; m < 4; ++m)                                                      \
            _Pragma("unroll")                                                            \
            for (int n = 0; n < 4; ++n)                                                  \
                acc[m][n] = __builtin_amdgcn_mfma_f32_16x16x32_bf16(af[m], bf[n], acc[m][n], 0, 0, 0); \
        __builtin_amdgcn_s_setprio(0);                                                   \
        __builtin_amdgcn_s_barrier();                                                    \
        if (kt + 2 < 32) STG(kt + 2);                                                    \
        if (kt < 30) { asm volatile("s_waitcnt vmcnt(3)" ::: "memory"); }                \
        else         { asm volatile("s_waitcnt vmcnt(0)" ::: "memory"); }                \
        __builtin_amdgcn_s_barrier();                                                    \
    }

// ---------------- GEMM1: [16384,3072] = x @ qkv_w^T, LDS-staged epilogue (R10) ----------
__global__ __launch_bounds__(512, 2) void k_gemm1_256(
    const u16* __restrict__ A, const u16* __restrict__ Bw,
    const float* __restrict__ bias, const float* __restrict__ pos_enc,
    u16* __restrict__ q, u16* __restrict__ ktg, u16* __restrict__ v, u16* __restrict__ vtg)
{
    __shared__ u16 lds[65536];   // K-loop dbuf, then 256x256 u16 C-tile
    const int lid = blockIdx.y * 12 + blockIdx.x;            // nwg = 768, %8==0
    const int swz = (lid & 7) * 96 + (lid >> 3);
    const int bcol = (swz % 12) * 256;
    const int brow = (swz / 12) * 256;

    GEMM256_2BAR()

    const int part = bcol >> 10;                 // 0=q 1=k 2=v, uniform per block
    {
        const int row_l = wr * 128 + (l >> 4) * 4;
        const int col_l = wc * 64 + fr;
        #pragma unroll
        for (int n = 0; n < 4; ++n) {
            const int col = col_l + n * 16;
            const int gc = bcol + col;
            const int c = gc & 1023;
            float bv = bias[gc];
            if (part == 1) bv += pos_enc[c];
            const int cc = col >> 3, in = col & 7;
            #pragma unroll
            for (int m = 0; m < 8; ++m)
                #pragma unroll
                for (int j = 0; j < 4; ++j) {
                    const int row = row_l + m * 16 + j;
                    float val = acc[m][n][j] + bv;
                    if (part != 2) val = fmaxf(val, 0.f);
                    lds[row * 256 + ((cc ^ (row & 7)) << 3) + in] = f2b(val);
                }
        }
    }
    __syncthreads();
    const int b_ = brow >> 12, i0 = brow & 4095;
    if (part != 1) {
        u16* dst = (part == 0) ? q : v;
        #pragma unroll
        for (int it = 0; it < 16; ++it) {
            const int id = it * 512 + t;
            const int row = id >> 5, cc = id & 31;
            short8 val = *reinterpret_cast<const short8*>(&lds[row * 256 + ((cc ^ (row & 7)) << 3)]);
            const int c2 = (bcol + cc * 8) & 1023;
            const int h2 = c2 >> 6, d2 = c2 & 63;
            *reinterpret_cast<short8*>(
                &dst[((size_t)(b_ * NH + h2) * NN + i0 + row) * HDIM + d2]) = val;
        }
    }
    if (part != 0) {
        u16* dstT = (part == 1) ? ktg : vtg;
        #pragma unroll
        for (int it = 0; it < 16; ++it) {
            const int id = it * 512 + t;
            const int cl = id & 255, jc = id >> 8;   // c-local, j-chunk (8 rows)
            short8 vv;
            #pragma unroll
            for (int rr = 0; rr < 8; ++rr)
                vv[rr] = (short)lds[(jc * 8 + rr) * 256 + (((cl >> 3) ^ rr) << 3) + (cl & 7)];
            const int c2 = (bcol + cl) & 1023;
            const int h2 = c2 >> 6, d2 = c2 & 63;
            *reinterpret_cast<short8*>(
                &dstT[((size_t)(b_ * NH + h2) * HDIM + d2) * NN + i0 + jc * 8]) = vv;
        }
    }
}

// ---------------- GEMM2: [16384,1024] = out2 @ proj_w^T + b, 128x256 tile --------------
__global__ __launch_bounds__(512, 3) void k_gemm2_128(
    const u16* __restrict__ A, const u16* __restrict__ Bw,
    const float* __restrict__ bias, float* __restrict__ out)
{
    __shared__ u16 lds[24576];   // 48KB: K-loop dbuf, then 32x256 fp32 C-quarter
    // bijective XCD swizzle: nwg = 4*128 = 512, %8==0
    const int lid = blockIdx.y * 4 + blockIdx.x;
    const int swz = (lid & 7) * 64 + (lid >> 3);
    const int bcol = (swz % 4) * 256;
    const int brow = (swz / 4) * 128;

    GEMM128x256()

    float* ldsf = reinterpret_cast<float*>(lds);     // 32 rows x 256 f32 = 32KB
    #pragma unroll 1
    for (int qp = 0; qp < 4; ++qp) {
        __syncthreads();
        if (wr == (qp >> 1)) {
            const int m0 = (qp & 1) * 2;
            const int row_l = (l >> 4) * 4;
            const int col_l = wc * 64 + fr;
            #pragma unroll
            for (int n = 0; n < 4; ++n) {
                const int col = col_l + n * 16;
                const float bv = bias[bcol + col];
                #pragma unroll
                for (int mm = 0; mm < 2; ++mm)
                    #pragma unroll
                    for (int j = 0; j < 4; ++j) {
                        const int row = mm * 16 + row_l + j;     // 0..31
                        ldsf[row * 256 + (col ^ (((row >> 2) & 3) << 3))] = acc[m0 + mm][n][j] + bv;
                    }
            }
        }
        __syncthreads();
        const float4* ldsf4 = reinterpret_cast<const float4*>(ldsf);
        #pragma unroll
        for (int it = 0; it < 4; ++it) {
            const int id = it * 512 + t;                 // 0..2047
            const int row = id >> 6, cc4 = id & 63;      // row 0..31
            float4 vv = ldsf4[row * 64 + (cc4 ^ (((row >> 2) & 3) << 1))];
            *reinterpret_cast<float4*>(
                &out[(size_t)(brow + qp * 32 + row) * CDIM + bcol + cc4 * 4]) = vv;
        }
    }
}

// ---------------- K2: kv via MFMA on transposed layouts (R10) ----------------
__global__ __launch_bounds__(256) void k_kv_mfma(
    const u16* __restrict__ ktg, const u16* __restrict__ vtg,
    float* __restrict__ part)   // [4 chunks][64 bh][5120]
{
    __shared__ float red[4][5120];
    const int t = threadIdx.x, l = t & 63, w = t >> 6;
    const int bh = blockIdx.x, ch = blockIdx.y;
    const u16* kb = ktg + (size_t)bh * HDIM * NN;
    const u16* vb = vtg + (size_t)bh * HDIM * NN;
    const int j0 = ch * 1024 + w * 256;
    const int fr = l & 15, kf = (l >> 4) * 8;

    f32x4 acc[5][4];
    #pragma unroll
    for (int m = 0; m < 5; ++m)
        #pragma unroll
        for (int n = 0; n < 4; ++n) acc[m][n] = (f32x4){0.f, 0.f, 0.f, 0.f};
    short8 ones;
    #pragma unroll
    for (int i = 0; i < 8; ++i) ones[i] = (short)0x3F80;

    for (int js = 0; js < 256; js += 32) {
        const int jb = j0 + js + kf;
        short8 a[4], b[4];
        #pragma unroll
        for (int m = 0; m < 4; ++m)
            a[m] = *reinterpret_cast<const short8*>(&vb[(size_t)(m * 16 + fr) * NN + jb]);
        #pragma unroll
        for (int n = 0; n < 4; ++n)
            b[n] = *reinterpret_cast<const short8*>(&kb[(size_t)(n * 16 + fr) * NN + jb]);
        #pragma unroll
        for (int m = 0; m < 4; ++m)
            #pragma unroll
            for (int n = 0; n < 4; ++n)
                acc[m][n] = __builtin_amdgcn_mfma_f32_16x16x32_bf16(a[m], b[n], acc[m][n], 0, 0, 0);
        #pragma unroll
        for (int n = 0; n < 4; ++n)
            acc[4][n] = __builtin_amdgcn_mfma_f32_16x16x32_bf16(ones, b[n], acc[4][n], 0, 0, 0);
    }
    #pragma unroll
    for (int m = 0; m < 5; ++m)
        #pragma unroll
        for (int n = 0; n < 4; ++n)
            #pragma unroll
            for (int j = 0; j < 4; ++j)
                red[w][(m * 16 + (l >> 4) * 4 + j) * 64 + fr + n * 16] = acc[m][n][j];
    __syncthreads();
    float* po = part + ((size_t)ch * BH + bh) * 5120;
    for (int i = t; i < 5120; i += 256)
        po[i] = red[0][i] + red[1][i] + red[2][i] + red[3][i];
}

__global__ __launch_bounds__(256) void k_kv_red(
    const float* __restrict__ part, u16* __restrict__ kvt)
{
    const int bh = blockIdx.x, t = threadIdx.x;
    u16* base = kvt + bh * 5120;
    for (int i = t; i < 5120; i += 256) {
        float s = part[(size_t)(0 * BH + bh) * 5120 + i]
                + part[(size_t)(1 * BH + bh) * 5120 + i]
                + part[(size_t)(2 * BH + bh) * 5120 + i]
                + part[(size_t)(3 * BH + bh) * 5120 + i];
        base[i] = f2b(s);
    }
}

// ---------------- K4: MFMA attention finish + depthwise conv (R10) ----------------
__global__ __launch_bounds__(256) void k_attn_mfma(
    const u16* __restrict__ q, const u16* __restrict__ v,
    const u16* __restrict__ kvt,
    const float* __restrict__ dwc_w, const float* __restrict__ dwc_b,
    u16* __restrict__ out2)
{
    __shared__ u16 att[4][64 * 68];
    const int t = threadIdx.x;
    const int l = t & 63, w = t >> 6;
    const int bh = blockIdx.x;
    const int tb = blockIdx.y * 256 + w * 64;
    const size_t hb = (size_t)bh * NN * HDIM;
    const u16* qb  = q + hb + (size_t)tb * HDIM;
    const u16* kvb = kvt + bh * 5120;

    const int fr = l & 15;
    const int kfrag = (l >> 4) * 8;

    short8 bfr[5][2];
    #pragma unroll
    for (int n = 0; n < 5; ++n)
        #pragma unroll
        for (int ks = 0; ks < 2; ++ks)
            bfr[n][ks] = *reinterpret_cast<const short8*>(&kvb[(n * 16 + fr) * 64 + ks * 32 + kfrag]);

    f32x4 acc[4][5];
    #pragma unroll
    for (int m = 0; m < 4; ++m)
        #pragma unroll
        for (int n = 0; n < 5; ++n) acc[m][n] = (f32x4){0.f, 0.f, 0.f, 0.f};

    #pragma unroll
    for (int m = 0; m < 4; ++m)
        #pragma unroll
        for (int ks = 0; ks < 2; ++ks) {
            short8 a = *reinterpret_cast<const short8*>(&qb[(m * 16 + fr) * 64 + ks * 32 + kfrag]);
            #pragma unroll
            for (int n = 0; n < 5; ++n)
                acc[m][n] = __builtin_amdgcn_mfma_f32_16x16x32_bf16(a, bfr[n][ks], acc[m][n], 0, 0, 0);
        }

    #pragma unroll
    for (int m = 0; m < 4; ++m)
        #pragma unroll
        for (int j = 0; j < 4; ++j) {
            const float den = __shfl(acc[m][4][j], l & 48);
            const float z = 1.f / (den + 1e-6f);
            const int row = m * 16 + (l >> 4) * 4 + j;
            #pragma unroll
            for (int n = 0; n < 4; ++n)
                att[w][row * 68 + fr + n * 16] = f2b(acc[m][n][j] * z);
        }
    __syncthreads();

    const int d = l;
    float w5[5];
    #pragma unroll
    for (int dh = 0; dh < 5; ++dh) w5[dh] = dwc_w[d * 25 + dh * 5 + 2];
    const float cbias = dwc_b[d];
    const int b_ = bh >> 4, h_ = bh & 15;
    u16* obase = out2 + (size_t)b_ * NN * CDIM + (size_t)h_ * 64 + d;
    float win[5];
    #pragma unroll
    for (int p = 0; p < 4; ++p) {
        const int src = tb - 2 + p;
        win[p] = (src >= 0 && src < NN) ? b2f(v[hb + (size_t)src * 64 + d]) : 0.f;
    }
    for (int it = 0; it < 64; ++it) {
        const int srcn = tb + it + 2;
        win[4] = (srcn < NN) ? b2f(v[hb + (size_t)srcn * 64 + d]) : 0.f;
        const float fm = cbias + w5[0] * win[0] + w5[1] * win[1] + w5[2] * win[2]
                               + w5[3] * win[3] + w5[4] * win[4];
        const float attn = b2f((short)att[w][it * 68 + d]);
        obase[(size_t)(tb + it) * CDIM] = f2b(attn + fm);
        win[0] = win[1]; win[1] = win[2]; win[2] = win[3]; win[3] = win[4];
    }
}

extern "C" void kernel_launch(void* const* d_in, const int* in_sizes, int n_in,
                              void* d_out, int out_size, void* d_ws, size_t ws_size,
                              hipStream_t stream)
{
    const float* x       = (const float*)d_in[0];
    const float* qkv_w   = (const float*)d_in[1];
    const float* qkv_b   = (const float*)d_in[2];
    const float* proj_w  = (const float*)d_in[3];
    const float* proj_b  = (const float*)d_in[4];
    const float* pos_enc = (const float*)d_in[5];
    const float* dwc_w   = (const float*)d_in[6];
    const float* dwc_b   = (const float*)d_in[7];

    const size_t QKV = 16777216;
    char* p = (char*)d_ws;
    u16* q_b    = (u16*)p;               p += QKV * 2;
    u16* ktg    = (u16*)p;               p += QKV * 2;  // reused as out2 after K2
    u16* v_b    = (u16*)p;               p += QKV * 2;
    u16* vtg    = (u16*)p;               p += QKV * 2;
    u16* x_b    = (u16*)p;               p += QKV * 2;
    u16* qkvw_b = (u16*)p;               p += (size_t)3145728 * 2;
    u16* projw_b= (u16*)p;               p += (size_t)1048576 * 2;
    float* part = (float*)p;             p += (size_t)4 * BH * 5120 * 4;
    u16* kvt    = (u16*)p;               p += (size_t)(BH * 5120) * 2;
    const size_t need_bytes = (size_t)(p - (char*)d_ws);

    if (ws_size < need_bytes) {
        const float diag = 4096.0f + (float)(ws_size >> 20);
        k_fill_diag<<<(out_size + 255) / 256, 256, 0, stream>>>((float*)d_out, out_size, diag);
        return;
    }

    u16* out2 = ktg;            // ktg dead after k_kv_mfma
    float* out = (float*)d_out;

    k_convert_all<<<20480, 256, 0, stream>>>(x, qkv_w, proj_w, x_b, qkvw_b, projw_b);

    k_gemm1_256 <<<dim3(12, 64), 512, 0, stream>>>(x_b, qkvw_b, qkv_b, pos_enc, q_b, ktg, v_b, vtg);
    k_kv_mfma   <<<dim3(64, 4),  256, 0, stream>>>(ktg, vtg, part);
    k_kv_red    <<<64,           256, 0, stream>>>(part, kvt);
    k_attn_mfma <<<dim3(64, 16), 256, 0, stream>>>(q_b, v_b, kvt, dwc_w, dwc_b, out2);
    k_gemm2_128 <<<dim3(4, 128), 512, 0, stream>>>(out2, projw_b, proj_b, out);
}

// Round 15
// 275.432 us; speedup vs baseline: 6.7070x; 1.1339x over previous
//
#include <hip/hip_runtime.h>

// SLabLinearAttention: B=4 N=4096 C=1024 H=16 HD=64 KH=5
// Round 15: REVERT to R10 verbatim (empirical best, 276.6us).
// R14's A/B showed gemm2@128x256 costs +36us (BK=32 halves MFMA-per-barrier);
// 256x256/BK=64 de-fenced 2-barrier core is the tested optimum for both GEMMs.

#define BB   4
#define NN   4096
#define CDIM 1024
#define NH   16
#define HDIM 64
#define BH   64

typedef __attribute__((ext_vector_type(8))) short short8;
typedef __attribute__((ext_vector_type(4))) float f32x4;
typedef unsigned short u16;

__device__ __forceinline__ float b2f(short s) {
    union { unsigned u; float f; } c;
    c.u = ((unsigned)(unsigned short)s) << 16;
    return c.f;
}
__device__ __forceinline__ u16 f2b(float f) {   // RNE
    unsigned u = __float_as_uint(f);
    return (u16)((u + 0x7fffu + ((u >> 16) & 1u)) >> 16);
}
__device__ __forceinline__ void gload16(const void* g, void* l) {
    __builtin_amdgcn_global_load_lds((const __attribute__((address_space(1))) void*)g,
                                     (__attribute__((address_space(3))) void*)l, 16, 0, 0);
}

__global__ __launch_bounds__(256) void k_fill_diag(float* __restrict__ out, int n, float val)
{
    int i = blockIdx.x * 256 + threadIdx.x;
    if (i < n) out[i] = val;
}

// fused convert: x (4194304 f4) | qkv_w (786432 f4) | proj_w (262144 f4)
__global__ __launch_bounds__(256) void k_convert_all(
    const float* __restrict__ x, const float* __restrict__ qw, const float* __restrict__ pw,
    u16* __restrict__ xb, u16* __restrict__ qwb, u16* __restrict__ pwb)
{
    int i = blockIdx.x * 256 + threadIdx.x;
    const float* src; u16* dst; int j;
    if (i < 4194304)      { src = x;  dst = xb;  j = i; }
    else if (i < 4980736) { src = qw; dst = qwb; j = i - 4194304; }
    else                  { src = pw; dst = pwb; j = i - 4980736; }
    float4 v = reinterpret_cast<const float4*>(src)[j];
    ushort4 o;
    o.x = f2b(v.x); o.y = f2b(v.y); o.z = f2b(v.z); o.w = f2b(v.w);
    reinterpret_cast<ushort4*>(dst)[j] = o;
}

// ======= de-fenced 2-barrier 256x256 BK=64 GEMM core (R10) =======
// LDS (u16): buf b @ b*32768; A @ +0 (kh*8192), B @ +16384 (kh*8192).
// phys chunk = chunk ^ ((row>>1)&3); pre-swizzled global src, swizzled ds_read.
// Ledger: iter kt reads buf[kt&1]; barrier (a) after phase-A MFMA retires kh0 reads
// before phase-B's STG(kt+2,kh0) overwrite; vmcnt(4) at boundary => kt+1 landed;
// barrier (b) publishes.
#define GEMM256_2BAR()                                                                   \
    const int t = threadIdx.x;                                                           \
    const int l = t & 63, w = t >> 6;                                                    \
    const int wr = w >> 2, wc = w & 3;                                                   \
    const int fr = l & 15;                                                               \
    const int physE  = ((l >> 4) ^ ((fr >> 1) & 3)) * 8;                                 \
    const int qa     = ((l & 3) ^ ((l >> 3) & 3)) * 8;                                   \
    const int aRow   = w * 16 + (l >> 2);                                                \
    const u16* gA0 = A  + (size_t)(brow + aRow) * 1024 + qa;                             \
    const u16* gB0 = Bw + (size_t)(bcol + aRow) * 1024 + qa;                             \
    char* ldsc = (char*)lds;                                                             \
    const int afBase = (wr * 128 + fr) * 32 + physE;                                     \
    const int bfBase = 16384 + (wc * 64 + fr) * 32 + physE;                              \
    f32x4 acc[8][4];                                                                     \
    _Pragma("unroll")                                                                    \
    for (int m = 0; m < 8; ++m)                                                          \
        _Pragma("unroll")                                                                \
        for (int n = 0; n < 4; ++n) acc[m][n] = (f32x4){0.f, 0.f, 0.f, 0.f};             \
    auto STG = [&](int kt, int kh, int isB) {                                            \
        const u16* g = (isB ? gB0 : gA0) + kt * 64 + kh * 32;                            \
        char* d = ldsc + (kt & 1) * 65536 + isB * 32768 + kh * 16384 + w * 1024 + l * 16;\
        gload16(g,          d);                                                          \
        gload16(g + 131072, d + 8192);                                                   \
    };                                                                                   \
    STG(0,0,0); STG(0,0,1); STG(0,1,0); STG(0,1,1); STG(1,0,0); STG(1,0,1);              \
    asm volatile("s_waitcnt vmcnt(4)" ::: "memory");                                     \
    __builtin_amdgcn_s_barrier();                                                        \
    _Pragma("unroll 1")                                                                  \
    for (int kt = 0; kt < 16; ++kt) {                                                    \
        const int B0 = (kt & 1) * 32768;                                                 \
        short8 af[8], bf[4];                                                             \
        /* ---- phase A: kh0 ---- */                                                     \
        _Pragma("unroll")                                                                \
        for (int n = 0; n < 4; ++n)                                                      \
            bf[n] = *reinterpret_cast<const short8*>(&lds[B0 + bfBase + n * 512]);       \
        _Pragma("unroll")                                                                \
        for (int m = 0; m < 8; ++m)                                                      \
            af[m] = *reinterpret_cast<const short8*>(&lds[B0 + afBase + m * 512]);       \
        if (kt + 1 < 16) { STG(kt + 1, 1, 0); STG(kt + 1, 1, 1); }                       \
        __builtin_amdgcn_s_setprio(1);                                                   \
        _Pragma("unroll")                                                                \
        for (int m = 0; m < 8; ++m)                                                      \
            _Pragma("unroll")                                                            \
            for (int n = 0; n < 4; ++n)                                                  \
                acc[m][n] = __builtin_amdgcn_mfma_f32_16x16x32_bf16(af[m], bf[n], acc[m][n], 0, 0, 0); \
        __builtin_amdgcn_s_setprio(0);                                                   \
        __builtin_amdgcn_s_barrier();   /* (a) kh0 reads retired before overwrite */     \
        /* ---- phase B: kh1 ---- */                                                     \
        _Pragma("unroll")                                                                \
        for (int n = 0; n < 4; ++n)                                                      \
            bf[n] = *reinterpret_cast<const short8*>(&lds[B0 + 8192 + bfBase + n * 512]);\
        _Pragma("unroll")                                                                \
        for (int m = 0; m < 8; ++m)                                                      \
            af[m] = *reinterpret_cast<const short8*>(&lds[B0 + 8192 + afBase + m * 512]);\
        if (kt + 2 < 16) { STG(kt + 2, 0, 0); STG(kt + 2, 0, 1); }                       \
        __builtin_amdgcn_s_setprio(1);                                                   \
        _Pragma("unroll")                                                                \
        for (int m = 0; m < 8; ++m)                                                      \
            _Pragma("unroll")                                                            \
            for (int n = 0; n < 4; ++n)                                                  \
                acc[m][n] = __builtin_amdgcn_mfma_f32_16x16x32_bf16(af[m], bf[n], acc[m][n], 0, 0, 0); \
        __builtin_amdgcn_s_setprio(0);                                                   \
        if (kt < 15) { asm volatile("s_waitcnt vmcnt(4)" ::: "memory"); }                \
        else         { asm volatile("s_waitcnt vmcnt(0)" ::: "memory"); }                \
        __builtin_amdgcn_s_barrier();   /* (b) staged tile kt+1 published */             \
    }

// ---------------- GEMM1: [16384,3072] = x @ qkv_w^T, LDS-staged epilogue ----------------
// Outputs: q_b[bh][j][d], v_b[bh][j][d] (row-major); ktg[bh][c][j], vtg[bh][d][j].
__global__ __launch_bounds__(512, 2) void k_gemm1_256(
    const u16* __restrict__ A, const u16* __restrict__ Bw,
    const float* __restrict__ bias, const float* __restrict__ pos_enc,
    u16* __restrict__ q, u16* __restrict__ ktg, u16* __restrict__ v, u16* __restrict__ vtg)
{
    __shared__ u16 lds[65536];   // K-loop dbuf, then 256x256 u16 C-tile
    const int lid = blockIdx.y * 12 + blockIdx.x;            // nwg = 768, %8==0
    const int swz = (lid & 7) * 96 + (lid >> 3);
    const int bcol = (swz % 12) * 256;
    const int brow = (swz / 12) * 256;

    GEMM256_2BAR()

    const int part = bcol >> 10;                 // 0=q 1=k 2=v, uniform per block
    {
        const int row_l = wr * 128 + (l >> 4) * 4;
        const int col_l = wc * 64 + fr;
        #pragma unroll
        for (int n = 0; n < 4; ++n) {
            const int col = col_l + n * 16;
            const int gc = bcol + col;
            const int c = gc & 1023;
            float bv = bias[gc];
            if (part == 1) bv += pos_enc[c];
            const int cc = col >> 3, in = col & 7;
            #pragma unroll
            for (int m = 0; m < 8; ++m)
                #pragma unroll
                for (int j = 0; j < 4; ++j) {
                    const int row = row_l + m * 16 + j;
                    float val = acc[m][n][j] + bv;
                    if (part != 2) val = fmaxf(val, 0.f);
                    lds[row * 256 + ((cc ^ (row & 7)) << 3) + in] = f2b(val);
                }
        }
    }
    __syncthreads();
    const int b_ = brow >> 12, i0 = brow & 4095;
    if (part != 1) {
        // row-major coalesced store: q_b or v_b  [bh][j][d]
        u16* dst = (part == 0) ? q : v;
        #pragma unroll
        for (int it = 0; it < 16; ++it) {
            const int id = it * 512 + t;
            const int row = id >> 5, cc = id & 31;
            short8 val = *reinterpret_cast<const short8*>(&lds[row * 256 + ((cc ^ (row & 7)) << 3)]);
            const int c2 = (bcol + cc * 8) & 1023;
            const int h2 = c2 >> 6, d2 = c2 & 63;
            *reinterpret_cast<short8*>(
                &dst[((size_t)(b_ * NH + h2) * NN + i0 + row) * HDIM + d2]) = val;
        }
    }
    if (part != 0) {
        // transposed coalesced store: ktg[bh][c][j] or vtg[bh][d][j]
        u16* dstT = (part == 1) ? ktg : vtg;
        #pragma unroll
        for (int it = 0; it < 16; ++it) {
            const int id = it * 512 + t;
            const int cl = id & 255, jc = id >> 8;   // c-local, j-chunk (8 rows)
            short8 vv;
            #pragma unroll
            for (int rr = 0; rr < 8; ++rr)
                vv[rr] = (short)lds[(jc * 8 + rr) * 256 + (((cl >> 3) ^ rr) << 3) + (cl & 7)];
            const int c2 = (bcol + cl) & 1023;
            const int h2 = c2 >> 6, d2 = c2 & 63;
            *reinterpret_cast<short8*>(
                &dstT[((size_t)(b_ * NH + h2) * HDIM + d2) * NN + i0 + jc * 8]) = vv;
        }
    }
}

// ---------------- GEMM2: [16384,1024] = out2 @ proj_w^T + b, coalesced fp32 out --------
__global__ __launch_bounds__(512, 2) void k_gemm2_256(
    const u16* __restrict__ A, const u16* __restrict__ Bw,
    const float* __restrict__ bias, float* __restrict__ out)
{
    __shared__ u16 lds[65536];
    const int lid = blockIdx.y * 4 + blockIdx.x;             // nwg = 256, %8==0
    const int swz = (lid & 7) * 32 + (lid >> 3);
    const int bcol = (swz % 4) * 256;
    const int brow = (swz / 4) * 256;

    GEMM256_2BAR()

    // LDS-staged epilogue: two 128x256 fp32 half-tiles; phys col = col ^ (((row>>2)&3)<<3)
    float* ldsf = reinterpret_cast<float*>(lds);
    #pragma unroll 1
    for (int half = 0; half < 2; ++half) {
        __syncthreads();
        if (wr == half) {
            const int row_l = (l >> 4) * 4;
            const int col_l = wc * 64 + fr;
            #pragma unroll
            for (int n = 0; n < 4; ++n) {
                const int col = col_l + n * 16;
                const float bv = bias[bcol + col];
                #pragma unroll
                for (int m = 0; m < 8; ++m)
                    #pragma unroll
                    for (int j = 0; j < 4; ++j) {
                        const int row = m * 16 + row_l + j;     // 0..127
                        ldsf[row * 256 + (col ^ (((row >> 2) & 3) << 3))] = acc[m][n][j] + bv;
                    }
            }
        }
        __syncthreads();
        const float4* ldsf4 = reinterpret_cast<const float4*>(ldsf);
        #pragma unroll
        for (int it = 0; it < 16; ++it) {
            const int id = it * 512 + t;                 // 0..8191
            const int row = id >> 6, cc4 = id & 63;
            float4 vv = ldsf4[row * 64 + (cc4 ^ (((row >> 2) & 3) << 1))];
            *reinterpret_cast<float4*>(
                &out[(size_t)(brow + half * 128 + row) * CDIM + bcol + cc4 * 4]) = vv;
        }
    }
}

// ---------------- K2: kv via MFMA on transposed layouts ----------------
__global__ __launch_bounds__(256) void k_kv_mfma(
    const u16* __restrict__ ktg, const u16* __restrict__ vtg,
    float* __restrict__ part)   // [4 chunks][64 bh][5120]
{
    __shared__ float red[4][5120];
    const int t = threadIdx.x, l = t & 63, w = t >> 6;
    const int bh = blockIdx.x, ch = blockIdx.y;
    const u16* kb = ktg + (size_t)bh * HDIM * NN;
    const u16* vb = vtg + (size_t)bh * HDIM * NN;
    const int j0 = ch * 1024 + w * 256;
    const int fr = l & 15, kf = (l >> 4) * 8;

    f32x4 acc[5][4];
    #pragma unroll
    for (int m = 0; m < 5; ++m)
        #pragma unroll
        for (int n = 0; n < 4; ++n) acc[m][n] = (f32x4){0.f, 0.f, 0.f, 0.f};
    short8 ones;
    #pragma unroll
    for (int i = 0; i < 8; ++i) ones[i] = (short)0x3F80;

    for (int js = 0; js < 256; js += 32) {
        const int jb = j0 + js + kf;
        short8 a[4], b[4];
        #pragma unroll
        for (int m = 0; m < 4; ++m)
            a[m] = *reinterpret_cast<const short8*>(&vb[(size_t)(m * 16 + fr) * NN + jb]);
        #pragma unroll
        for (int n = 0; n < 4; ++n)
            b[n] = *reinterpret_cast<const short8*>(&kb[(size_t)(n * 16 + fr) * NN + jb]);
        #pragma unroll
        for (int m = 0; m < 4; ++m)
            #pragma unroll
            for (int n = 0; n < 4; ++n)
                acc[m][n] = __builtin_amdgcn_mfma_f32_16x16x32_bf16(a[m], b[n], acc[m][n], 0, 0, 0);
        #pragma unroll
        for (int n = 0; n < 4; ++n)
            acc[4][n] = __builtin_amdgcn_mfma_f32_16x16x32_bf16(ones, b[n], acc[4][n], 0, 0, 0);
    }
    #pragma unroll
    for (int m = 0; m < 5; ++m)
        #pragma unroll
        for (int n = 0; n < 4; ++n)
            #pragma unroll
            for (int j = 0; j < 4; ++j)
                red[w][(m * 16 + (l >> 4) * 4 + j) * 64 + fr + n * 16] = acc[m][n][j];
    __syncthreads();
    float* po = part + ((size_t)ch * BH + bh) * 5120;
    for (int i = t; i < 5120; i += 256)
        po[i] = red[0][i] + red[1][i] + red[2][i] + red[3][i];
}

__global__ __launch_bounds__(256) void k_kv_red(
    const float* __restrict__ part, u16* __restrict__ kvt)
{
    const int bh = blockIdx.x, t = threadIdx.x;
    u16* base = kvt + bh * 5120;
    for (int i = t; i < 5120; i += 256) {
        float s = part[(size_t)(0 * BH + bh) * 5120 + i]
                + part[(size_t)(1 * BH + bh) * 5120 + i]
                + part[(size_t)(2 * BH + bh) * 5120 + i]
                + part[(size_t)(3 * BH + bh) * 5120 + i];
        base[i] = f2b(s);
    }
}

// ---------------- K4: MFMA attention finish + depthwise conv (coalesced v_b) ------------
__global__ __launch_bounds__(256) void k_attn_mfma(
    const u16* __restrict__ q, const u16* __restrict__ v,
    const u16* __restrict__ kvt,
    const float* __restrict__ dwc_w, const float* __restrict__ dwc_b,
    u16* __restrict__ out2)
{
    __shared__ u16 att[4][64 * 68];
    const int t = threadIdx.x;
    const int l = t & 63, w = t >> 6;
    const int bh = blockIdx.x;
    const int tb = blockIdx.y * 256 + w * 64;
    const size_t hb = (size_t)bh * NN * HDIM;
    const u16* qb  = q + hb + (size_t)tb * HDIM;
    const u16* kvb = kvt + bh * 5120;

    const int fr = l & 15;
    const int kfrag = (l >> 4) * 8;

    short8 bfr[5][2];
    #pragma unroll
    for (int n = 0; n < 5; ++n)
        #pragma unroll
        for (int ks = 0; ks < 2; ++ks)
            bfr[n][ks] = *reinterpret_cast<const short8*>(&kvb[(n * 16 + fr) * 64 + ks * 32 + kfrag]);

    f32x4 acc[4][5];
    #pragma unroll
    for (int m = 0; m < 4; ++m)
        #pragma unroll
        for (int n = 0; n < 5; ++n) acc[m][n] = (f32x4){0.f, 0.f, 0.f, 0.f};

    #pragma unroll
    for (int m = 0; m < 4; ++m)
        #pragma unroll
        for (int ks = 0; ks < 2; ++ks) {
            short8 a = *reinterpret_cast<const short8*>(&qb[(m * 16 + fr) * 64 + ks * 32 + kfrag]);
            #pragma unroll
            for (int n = 0; n < 5; ++n)
                acc[m][n] = __builtin_amdgcn_mfma_f32_16x16x32_bf16(a, bfr[n][ks], acc[m][n], 0, 0, 0);
        }

    #pragma unroll
    for (int m = 0; m < 4; ++m)
        #pragma unroll
        for (int j = 0; j < 4; ++j) {
            const float den = __shfl(acc[m][4][j], l & 48);
            const float z = 1.f / (den + 1e-6f);
            const int row = m * 16 + (l >> 4) * 4 + j;
            #pragma unroll
            for (int n = 0; n < 4; ++n)
                att[w][row * 68 + fr + n * 16] = f2b(acc[m][n][j] * z);
        }
    __syncthreads();

    const int d = l;
    float w5[5];
    #pragma unroll
    for (int dh = 0; dh < 5; ++dh) w5[dh] = dwc_w[d * 25 + dh * 5 + 2];
    const float cbias = dwc_b[d];
    const int b_ = bh >> 4, h_ = bh & 15;
    u16* obase = out2 + (size_t)b_ * NN * CDIM + (size_t)h_ * 64 + d;
    float win[5];
    #pragma unroll
    for (int p = 0; p < 4; ++p) {
        const int src = tb - 2 + p;
        win[p] = (src >= 0 && src < NN) ? b2f(v[hb + (size_t)src * 64 + d]) : 0.f;
    }
    for (int it = 0; it < 64; ++it) {
        const int srcn = tb + it + 2;
        win[4] = (srcn < NN) ? b2f(v[hb + (size_t)srcn * 64 + d]) : 0.f;
        const float fm = cbias + w5[0] * win[0] + w5[1] * win[1] + w5[2] * win[2]
                               + w5[3] * win[3] + w5[4] * win[4];
        const float attn = b2f((short)att[w][it * 68 + d]);
        obase[(size_t)(tb + it) * CDIM] = f2b(attn + fm);
        win[0] = win[1]; win[1] = win[2]; win[2] = win[3]; win[3] = win[4];
    }
}

extern "C" void kernel_launch(void* const* d_in, const int* in_sizes, int n_in,
                              void* d_out, int out_size, void* d_ws, size_t ws_size,
                              hipStream_t stream)
{
    const float* x       = (const float*)d_in[0];
    const float* qkv_w   = (const float*)d_in[1];
    const float* qkv_b   = (const float*)d_in[2];
    const float* proj_w  = (const float*)d_in[3];
    const float* proj_b  = (const float*)d_in[4];
    const float* pos_enc = (const float*)d_in[5];
    const float* dwc_w   = (const float*)d_in[6];
    const float* dwc_b   = (const float*)d_in[7];

    const size_t QKV = 16777216;
    char* p = (char*)d_ws;
    u16* q_b    = (u16*)p;               p += QKV * 2;
    u16* ktg    = (u16*)p;               p += QKV * 2;  // reused as out2 after K2
    u16* v_b    = (u16*)p;               p += QKV * 2;
    u16* vtg    = (u16*)p;               p += QKV * 2;
    u16* x_b    = (u16*)p;               p += QKV * 2;
    u16* qkvw_b = (u16*)p;               p += (size_t)3145728 * 2;
    u16* projw_b= (u16*)p;               p += (size_t)1048576 * 2;
    float* part = (float*)p;             p += (size_t)4 * BH * 5120 * 4;
    u16* kvt    = (u16*)p;               p += (size_t)(BH * 5120) * 2;
    const size_t need_bytes = (size_t)(p - (char*)d_ws);

    if (ws_size < need_bytes) {
        const float diag = 4096.0f + (float)(ws_size >> 20);
        k_fill_diag<<<(out_size + 255) / 256, 256, 0, stream>>>((float*)d_out, out_size, diag);
        return;
    }

    u16* out2 = ktg;            // ktg dead after k_kv_mfma
    float* out = (float*)d_out;

    k_convert_all<<<20480, 256, 0, stream>>>(x, qkv_w, proj_w, x_b, qkvw_b, projw_b);

    k_gemm1_256 <<<dim3(12, 64), 512, 0, stream>>>(x_b, qkvw_b, qkv_b, pos_enc, q_b, ktg, v_b, vtg);
    k_kv_mfma   <<<dim3(64, 4),  256, 0, stream>>>(ktg, vtg, part);
    k_kv_red    <<<64,           256, 0, stream>>>(part, kvt);
    k_attn_mfma <<<dim3(64, 16), 256, 0, stream>>>(q_b, v_b, kvt, dwc_w, dwc_b, out2);
    k_gemm2_256 <<<dim3(4, 64),  512, 0, stream>>>(out2, projw_b, proj_b, out);
}